// Round 3
// baseline (1112.737 us; speedup 1.0000x reference)
//
#include <hip/hip_runtime.h>

#define W 1024
#define H 1024
#define TR 32                 // tile rows per block
#define TC 64                 // tile cols per block
#define NBX 16                // col tiles
#define NBY 32                // row tiles
#define NBLK (NBX * NBY)      // 512 blocks == 2 per CU (co-resident by construction)
#define NT 512                // threads: 32 rows x 16 col-groups of 4 px
#define LST 72                // LDS row stride (words): ring col at 3 and 68, px at 4..67
#define LROWS 34              // 32 rows + 1 ring each side
#define LBUF (LROWS * LST)    // 2448 floats per h buffer
#define NPIX (H * W)
#define BSTR 256              // border slot stride per block (floats): top[0,64) bot[64,128) left[128,160) right[160,192)
#define SPIN_CAP 1000000
#define LOG2E 1.4426950408889634f
#define TWOL  2.8853900817779268f   // 2*log2(e)

typedef float v2f __attribute__((ext_vector_type(2)));

__device__ __forceinline__ float frcp_(float v) { return __builtin_amdgcn_rcpf(v); }
__device__ __forceinline__ float exp2_(float v) { return __builtin_amdgcn_exp2f(v); }
// Weights pre-scaled by init_ws: i,f,o rows by log2(e), g row by 2*log2(e).
__device__ __forceinline__ float sigm2_(float v)  { return frcp_(1.0f + exp2_(-v)); }
__device__ __forceinline__ float tanhg2_(float v) { return 1.0f - 2.0f * frcp_(1.0f + exp2_(v)); }
__device__ __forceinline__ float tanhc_(float v)  { return 1.0f - 2.0f * frcp_(1.0f + exp2_(TWOL * v)); }

// Zero the flags and write log2e-scaled weights. Runs before the persistent
// kernel on the same stream each launch/replay (re-arms the sync protocol).
__global__ __launch_bounds__(NT) void init_ws(const float* __restrict__ ew,
                                              const float* __restrict__ eb,
                                              const float* __restrict__ dw,
                                              const float* __restrict__ db,
                                              int* __restrict__ flags,
                                              float* __restrict__ wsc) {
    const int t = threadIdx.x;
    if (t < NBLK) flags[t] = 0;
    if (t < 72)                   wsc[t] = ew[t] * ((t / 18 == 3) ? TWOL : LOG2E);
    else if (t < 76)              wsc[t] = eb[t - 72] * ((t == 75) ? TWOL : LOG2E);
    else if (t >= 80 && t < 152)  wsc[t] = dw[t - 80] * (((t - 80) / 18 == 3) ? TWOL : LOG2E);
    else if (t >= 152 && t < 156) wsc[t] = db[t - 152] * ((t == 155) ? TWOL : LOG2E);
}

// One conv-input row for a 4-px slot: 6 floats (cols c-1 .. c+4).
struct R6 { float lm; float4 m; float rp; };

__device__ __forceinline__ R6 ld6(const float* __restrict__ p) {
    R6 r; r.lm = p[-1]; r.m = *(const float4*)p; r.rp = p[4]; return r;
}

// Raw-frame row load with SAME zero padding (float4 always in-bounds when row is).
__device__ __forceinline__ R6 ldx_row(const float* __restrict__ fr, int ry, int cq) {
    R6 r; r.m = make_float4(0.f, 0.f, 0.f, 0.f); r.lm = 0.f; r.rp = 0.f;
    if ((unsigned)ry < (unsigned)H) {
        const float* p = fr + (size_t)ry * W + cq;
        r.m = *(const float4*)p;
        if (cq > 0)     r.lm = p[-1];
        if (cq + 4 < W) r.rp = p[4];
    }
    return r;
}

// Accumulate one conv row (3 taps, 4 gates, 2 output pairs) into acc.
__device__ __forceinline__ void acc_row4(const R6& R, const float* __restrict__ wg,
                                         int wofs, v2f acc[4][2]) {
    const v2f E0 = {R.m.x, R.m.y}, E1 = {R.m.z, R.m.w};
    const v2f O0 = {R.lm, R.m.x}, O1 = {R.m.y, R.m.z}, O2 = {R.m.w, R.rp};
#pragma unroll
    for (int co = 0; co < 4; ++co) {
        const float w0 = wg[co * 18 + wofs + 0];
        const float w1 = wg[co * 18 + wofs + 1];
        const float w2 = wg[co * 18 + wofs + 2];
        const v2f W0 = {w0, w0}, W1 = {w1, w1}, W2 = {w2, w2};
        acc[co][0] += W0 * O0; acc[co][0] += W1 * E0; acc[co][0] += W2 * O1;
        acc[co][1] += W0 * O1; acc[co][1] += W1 * E1; acc[co][1] += W2 * O2;
    }
}

// First conv row of a step: first tap writes acc with `init` as the fma addend
// (BCAST: bias init[co]; else init[co*2+jp], e.g. the hoisted decoder x-conv).
template<bool BCAST>
__device__ __forceinline__ void acc_row4_init(const R6& R, const float* __restrict__ wg,
                                              int wofs, v2f acc[4][2],
                                              const v2f* __restrict__ init) {
    const v2f E0 = {R.m.x, R.m.y}, E1 = {R.m.z, R.m.w};
    const v2f O0 = {R.lm, R.m.x}, O1 = {R.m.y, R.m.z}, O2 = {R.m.w, R.rp};
#pragma unroll
    for (int co = 0; co < 4; ++co) {
        const float w0 = wg[co * 18 + wofs + 0];
        const float w1 = wg[co * 18 + wofs + 1];
        const float w2 = wg[co * 18 + wofs + 2];
        const v2f W0 = {w0, w0}, W1 = {w1, w1}, W2 = {w2, w2};
        const v2f b0 = BCAST ? init[co] : init[co * 2 + 0];
        const v2f b1 = BCAST ? init[co] : init[co * 2 + 1];
        acc[co][0] = W0 * O0 + b0; acc[co][0] += W1 * E0; acc[co][0] += W2 * O1;
        acc[co][1] = W0 * O1 + b1; acc[co][1] += W1 * E1; acc[co][1] += W2 * O2;
    }
}

// Persistent conv-LSTM: all 40 steps (20 enc + 20 dec) in one kernel with
// neighbor-only sync. 512 blocks (32x16 tiles of 32x64), 512 threads, 2
// blocks/CU guaranteed co-resident (<=128 VGPR via waves_per_eu(4,4), 19.6KB
// LDS). Per step: compute -> agent-scope border stores -> barrier -> release
// flag -> 196-thread crew spins on 8 neighbor flags, agent-loads the 196-px
// ring into the LDS ring -> barrier. Border buffers rotate mod 3 (skew <= 1).
__global__ __launch_bounds__(NT)
__attribute__((amdgpu_waves_per_eu(4, 4)))
void convlstm(const float* __restrict__ data,
              int* __restrict__ flags,
              float* __restrict__ bord,
              const float* __restrict__ wsc,
              float* __restrict__ dout)
{
    __shared__ float lds[2 * LBUF];
    const int tid = threadIdx.x;
    const int bid = blockIdx.x;
    const int bx = bid & (NBX - 1), by = bid >> 4;
    const int c0 = bx * TC, r0 = by * TR;
    const int r = tid >> 4, g = tid & 15;
    const int gr = r0 + r;
    const int cq = c0 + 4 * g;

    const float* wE = wsc;            // scaled enc weights [4][2][3][3]
    const float* bE = wsc + 72;
    const float* wD = wsc + 80;
    const float* bD = wsc + 152;

    const bool hNn = by > 0, hSn = by < NBY - 1, hWn = bx > 0, hEn = bx < NBX - 1;
    const int nN = hNn ? bid - NBX : -1, nS = hSn ? bid + NBX : -1;
    const int nWb = hWn ? bid - 1 : -1,  nEb = hEn ? bid + 1 : -1;
    const int nNW = (hNn && hWn) ? bid - NBX - 1 : -1, nNE = (hNn && hEn) ? bid - NBX + 1 : -1;
    const int nSW = (hSn && hWn) ? bid + NBX - 1 : -1, nSE = (hSn && hEn) ? bid + NBX + 1 : -1;

    // ---- ring-fetch crew assignment: 196 ring px, 1 per thread ----
    // top ring (row -1, cols -1..64): tid 0..65; bottom (row 32): 66..131;
    // left (col -1, rows 0..31): 132..163; right (col 64): 164..195.
    int csrc = -1, cidx = 0, cdst = 0;
    const bool crew = tid < 196;
    if (tid < 66) {
        const int q = tid - 1;
        cdst = 4 + q;
        if (q < 0)       { csrc = nNW; cidx = 64 + 63; }
        else if (q > 63) { csrc = nNE; cidx = 64 + 0; }
        else             { csrc = nN;  cidx = 64 + q; }
    } else if (tid < 132) {
        const int q = tid - 67;
        cdst = 33 * LST + 4 + q;
        if (q < 0)       { csrc = nSW; cidx = 63; }
        else if (q > 63) { csrc = nSE; cidx = 0; }
        else             { csrc = nS;  cidx = q; }
    } else if (tid < 164) {
        const int rr = tid - 132;
        cdst = (1 + rr) * LST + 3;  csrc = nWb; cidx = 160 + rr;   // W's right col
    } else if (tid < 196) {
        const int rr = tid - 164;
        cdst = (1 + rr) * LST + 68; csrc = nEb; cidx = 128 + rr;   // E's left col
    }

    // ---- zero buf0 (= h_0, including ring) ----
    float4* l4 = (float4*)lds;
#pragma unroll 1
    for (int k = tid; k < LBUF / 4; k += NT) l4[k] = make_float4(0.f, 0.f, 0.f, 0.f);

    v2f be[4], bd[4];
#pragma unroll
    for (int co = 0; co < 4; ++co) {
        be[co] = (v2f){bE[co], bE[co]};
        bd[co] = (v2f){bD[co], bD[co]};
    }

    float cc[4] = {0.f, 0.f, 0.f, 0.f};
    float hh[4] = {0.f, 0.f, 0.f, 0.f};

    // prefetch frame 0
    R6 px0 = ldx_row(data, gr - 1, cq);
    R6 px1 = ldx_row(data, gr,     cq);
    R6 px2 = ldx_row(data, gr + 1, cq);

    __syncthreads();

    int istep = 1, ib = 1;                      // ib = istep % 3
    const int hofs  = r * LST + 4 + 4 * g;      // read base: LDS row of gr-1
    const int wofs_ = (1 + r) * LST + 4 + 4 * g;

    // =================== encoder: steps 1..20 ===================
#pragma unroll 1
    for (int d = 1; d <= 20; ++d) {
        const float* hR = lds + ((d - 1) & 1) * LBUF;
        float*       hW = lds + (d & 1) * LBUF;
        v2f acc[4][2];
        acc_row4_init<true>(px0, wE, 0, acc, be);
        acc_row4(px1, wE, 3, acc);
        acc_row4(px2, wE, 6, acc);
        if (d < 20) {                            // prefetch next frame (18 regs)
            const float* fr = data + (size_t)d * NPIX;
            px0 = ldx_row(fr, gr - 1, cq);
            px1 = ldx_row(fr, gr,     cq);
            px2 = ldx_row(fr, gr + 1, cq);
        }
        {
            const float* hp = hR + hofs;
            const R6 h0 = ld6(hp), h1 = ld6(hp + LST), h2 = ld6(hp + 2 * LST);
            acc_row4(h0, wE, 9, acc);
            acc_row4(h1, wE, 12, acc);
            acc_row4(h2, wE, 15, acc);
        }
#pragma unroll
        for (int jp = 0; jp < 2; ++jp)
#pragma unroll
            for (int s = 0; s < 2; ++s) {
                const int e = 2 * jp + s;
                const float gi = sigm2_(acc[0][jp][s]);
                const float gf = sigm2_(acc[1][jp][s]);
                const float go = sigm2_(acc[2][jp][s]);
                const float gg = tanhg2_(acc[3][jp][s]);
                const float cn = gf * cc[e] + gi * gg;
                cc[e] = cn;
                hh[e] = go * tanhc_(cn);
            }
        *(float4*)(hW + wofs_) = make_float4(hh[0], hh[1], hh[2], hh[3]);
        {
            float* bp = bord + ((size_t)ib * NBLK + bid) * BSTR;
            if (r == 0) {
#pragma unroll
                for (int s = 0; s < 4; ++s)
                    __hip_atomic_store(bp + 4 * g + s, hh[s], __ATOMIC_RELAXED, __HIP_MEMORY_SCOPE_AGENT);
            }
            if (r == TR - 1) {
#pragma unroll
                for (int s = 0; s < 4; ++s)
                    __hip_atomic_store(bp + 64 + 4 * g + s, hh[s], __ATOMIC_RELAXED, __HIP_MEMORY_SCOPE_AGENT);
            }
            if (g == 0)  __hip_atomic_store(bp + 128 + r, hh[0], __ATOMIC_RELAXED, __HIP_MEMORY_SCOPE_AGENT);
            if (g == 15) __hip_atomic_store(bp + 160 + r, hh[3], __ATOMIC_RELAXED, __HIP_MEMORY_SCOPE_AGENT);
        }
        __syncthreads();   // LDS writes visible; barrier drains vmcnt -> border stores done
        if (tid == 0)
            __hip_atomic_store(flags + bid, istep, __ATOMIC_RELEASE, __HIP_MEMORY_SCOPE_AGENT);
        if (crew) {
            float v = 0.f;
            if (csrc >= 0) {
                int spins = 0;
                while (__hip_atomic_load(flags + csrc, __ATOMIC_RELAXED, __HIP_MEMORY_SCOPE_AGENT) < istep) {
                    __builtin_amdgcn_s_sleep(1);
                    if (++spins > SPIN_CAP) break;
                }
                __builtin_amdgcn_fence(__ATOMIC_ACQUIRE, "agent");
                v = __hip_atomic_load(bord + ((size_t)ib * NBLK + csrc) * BSTR + cidx,
                                      __ATOMIC_RELAXED, __HIP_MEMORY_SCOPE_AGENT);
            }
            hW[cdst] = v;
        }
        __syncthreads();
        ++istep; ib = (ib == 2) ? 0 : ib + 1;
    }

    // ======= transition: hoist decoder x-conv (x = h_enc, constant) =======
    v2f xacc[4][2];
    {
        const float* hp = lds + hofs;            // buf0 = complete h_enc (tile + ring)
        const R6 a0 = ld6(hp), a1 = ld6(hp + LST), a2 = ld6(hp + 2 * LST);
        acc_row4_init<true>(a0, wD, 0, xacc, bd);
        acc_row4(a1, wD, 3, xacc);
        acc_row4(a2, wD, 6, xacc);
    }
    __syncthreads();                             // everyone done reading buf0
#pragma unroll 1
    for (int k = tid; k < LBUF / 4; k += NT) l4[k] = make_float4(0.f, 0.f, 0.f, 0.f);
#pragma unroll
    for (int e = 0; e < 4; ++e) cc[e] = 0.f;
    __syncthreads();                             // buf0 = h_dec_0 = 0

    // =================== decoder: steps 21..40 ===================
#pragma unroll 1
    for (int d = 1; d <= 20; ++d) {
        const float* hR = lds + ((istep - 1) & 1) * LBUF;   // istep = 20+d
        float*       hW = lds + (istep & 1) * LBUF;
        v2f acc[4][2];
        {
            const float* hp = hR + hofs;
            const R6 h0 = ld6(hp), h1 = ld6(hp + LST), h2 = ld6(hp + 2 * LST);
            acc_row4_init<false>(h0, wD, 9, acc, &xacc[0][0]);
            acc_row4(h1, wD, 12, acc);
            acc_row4(h2, wD, 15, acc);
        }
#pragma unroll
        for (int jp = 0; jp < 2; ++jp)
#pragma unroll
            for (int s = 0; s < 2; ++s) {
                const int e = 2 * jp + s;
                const float gi = sigm2_(acc[0][jp][s]);
                const float gf = sigm2_(acc[1][jp][s]);
                const float go = sigm2_(acc[2][jp][s]);
                const float gg = tanhg2_(acc[3][jp][s]);
                const float cn = gf * cc[e] + gi * gg;
                cc[e] = cn;
                hh[e] = go * tanhc_(cn);
            }
        if (d == 20) break;                      // hh = final output px
        *(float4*)(hW + wofs_) = make_float4(hh[0], hh[1], hh[2], hh[3]);
        {
            float* bp = bord + ((size_t)ib * NBLK + bid) * BSTR;
            if (r == 0) {
#pragma unroll
                for (int s = 0; s < 4; ++s)
                    __hip_atomic_store(bp + 4 * g + s, hh[s], __ATOMIC_RELAXED, __HIP_MEMORY_SCOPE_AGENT);
            }
            if (r == TR - 1) {
#pragma unroll
                for (int s = 0; s < 4; ++s)
                    __hip_atomic_store(bp + 64 + 4 * g + s, hh[s], __ATOMIC_RELAXED, __HIP_MEMORY_SCOPE_AGENT);
            }
            if (g == 0)  __hip_atomic_store(bp + 128 + r, hh[0], __ATOMIC_RELAXED, __HIP_MEMORY_SCOPE_AGENT);
            if (g == 15) __hip_atomic_store(bp + 160 + r, hh[3], __ATOMIC_RELAXED, __HIP_MEMORY_SCOPE_AGENT);
        }
        __syncthreads();
        if (tid == 0)
            __hip_atomic_store(flags + bid, istep, __ATOMIC_RELEASE, __HIP_MEMORY_SCOPE_AGENT);
        if (crew) {
            float v = 0.f;
            if (csrc >= 0) {
                int spins = 0;
                while (__hip_atomic_load(flags + csrc, __ATOMIC_RELAXED, __HIP_MEMORY_SCOPE_AGENT) < istep) {
                    __builtin_amdgcn_s_sleep(1);
                    if (++spins > SPIN_CAP) break;
                }
                __builtin_amdgcn_fence(__ATOMIC_ACQUIRE, "agent");
                v = __hip_atomic_load(bord + ((size_t)ib * NBLK + csrc) * BSTR + cidx,
                                      __ATOMIC_RELAXED, __HIP_MEMORY_SCOPE_AGENT);
            }
            hW[cdst] = v;
        }
        __syncthreads();
        ++istep; ib = (ib == 2) ? 0 : ib + 1;
    }

    *(float4*)(dout + (size_t)gr * W + cq) = make_float4(hh[0], hh[1], hh[2], hh[3]);
}

extern "C" void kernel_launch(void* const* d_in, const int* in_sizes, int n_in,
                              void* d_out, int out_size, void* d_ws, size_t ws_size,
                              hipStream_t stream) {
    const float* data  = (const float*)d_in[0];  // [20,1,1,1024,1024]
    const float* enc_w = (const float*)d_in[1];  // [4,2,3,3]
    const float* enc_b = (const float*)d_in[2];  // [4]
    const float* dec_w = (const float*)d_in[3];
    const float* dec_b = (const float*)d_in[4];
    // d_in[5..7] = epoch(0), T_en(20), T_de(20): constant device scalars;
    // loop counts hardcoded (host can't read device memory under capture).

    float* ws    = (float*)d_ws;
    int*   flags = (int*)ws;                      // [512]
    float* bord  = ws + 512;                      // [3][512][256] border slots
    float* wsc   = bord + 3 * NBLK * BSTR;        // scaled weights (156 floats)
    float* dout  = (float*)d_out;
    // ws use: ~1.6 MB

    init_ws<<<1, NT, 0, stream>>>(enc_w, enc_b, dec_w, dec_b, flags, wsc);
    convlstm<<<NBLK, NT, 0, stream>>>(data, flags, bord, wsc, dout);
}

// Round 4
// 644.859 us; speedup vs baseline: 1.7256x; 1.7256x over previous
//
#include <hip/hip_runtime.h>

#define W 1024
#define H 1024
#define PADX 16                       // col zero-pad each side (state/h buffers)
#define PADY 8                        // row zero-pad each side
#define XS 1056                       // padded row stride (floats)
#define YS 1040                       // padded row count
#define FR ((size_t)XS * (size_t)YS)  // floats per padded buffer
#define NPIX (H * W)
#define TROWS 32                      // tile rows per block
#define TCOLS 64                      // tile cols per block
#define LRN 48                        // local rows: gr in [r0-8, r0+40)
#define LCV 96                        // valid local cols: gc in [c0-16, c0+80)
#define LCW 100                       // LDS row stride (pad 4 to stagger banks)
#define NSLOT 460                     // 46 rows x 10 col-groups (8 px each)
#define NB 512
#define LOG2E 1.4426950408889634f
#define TWOL  2.8853900817779268f     // 2*log2(e)

typedef float v2f __attribute__((ext_vector_type(2)));

__device__ __forceinline__ float frcp_(float v) { return __builtin_amdgcn_rcpf(v); }
__device__ __forceinline__ float exp2_(float v) { return __builtin_amdgcn_exp2f(v); }
// Gate pre-activations arrive pre-scaled by init_ws: i,f,o rows by log2(e),
// g row by 2*log2(e). So the exp2 needs no per-element multiply.
__device__ __forceinline__ float sigm2_(float v)  { return frcp_(1.0f + exp2_(-v)); }
__device__ __forceinline__ float tanhg2_(float v) { return 1.0f - 2.0f * frcp_(1.0f + exp2_(v)); }
__device__ __forceinline__ float tanhc_(float v)  { return 1.0f - 2.0f * frcp_(1.0f + exp2_(TWOL * v)); }

// Zero the 6 padded state buffers (ws[0..6FR)) and write log2e-scaled weight
// copies at ws+6FR:  enc_w[0..72) enc_b[72..76) dec_w[80..152) dec_b[152..156).
__global__ __launch_bounds__(256) void init_ws(const float* __restrict__ ew,
                                               const float* __restrict__ eb,
                                               const float* __restrict__ dw,
                                               const float* __restrict__ db,
                                               float* __restrict__ ws) {
    const size_t n4 = 6 * (FR / 4);
    size_t i = (size_t)blockIdx.x * blockDim.x + threadIdx.x;
    const size_t stride = (size_t)gridDim.x * blockDim.x;
    float4* w4 = (float4*)ws;
    const float4 z = make_float4(0.f, 0.f, 0.f, 0.f);
    for (; i < n4; i += stride) w4[i] = z;
    if (blockIdx.x == 0) {
        float* wsc = ws + 6 * FR;
        const int t = threadIdx.x;
        if (t < 72)                   wsc[t] = ew[t] * ((t / 18 == 3) ? TWOL : LOG2E);
        else if (t < 76)              wsc[t] = eb[t - 72] * ((t - 72 == 3) ? TWOL : LOG2E);
        else if (t >= 80 && t < 152)  wsc[t] = dw[t - 80] * (((t - 80) / 18 == 3) ? TWOL : LOG2E);
        else if (t >= 152 && t < 156) wsc[t] = db[t - 152] * ((t - 152 == 3) ? TWOL : LOG2E);
    }
}

// One conv-input row for an 8-px slot: 10 floats (cols gc0-1 .. gc0+8).
struct HRow { float4 A, B; float lm, rp; };

__device__ __forceinline__ HRow ld_row(const float* __restrict__ p) {
    HRow r;
    r.A  = *(const float4*)p;
    r.B  = *(const float4*)(p + 4);
    r.lm = p[-1];
    r.rp = p[8];
    return r;
}

// Masked raw-frame row load (SAME zero padding at image borders).
__device__ __forceinline__ HRow ld_xrow_edge(const float* __restrict__ base, int ry, int gc0) {
    HRow r;
    r.A = make_float4(0.f, 0.f, 0.f, 0.f);
    r.B = r.A;
    r.lm = 0.f; r.rp = 0.f;
    if ((unsigned)ry < (unsigned)H) {
        const float* row = base + (size_t)ry * W;
        if ((unsigned)gc0 < (unsigned)W) {
            r.A = *(const float4*)(row + gc0);
            r.B = *(const float4*)(row + gc0 + 4);
        }
        if ((unsigned)(gc0 - 1) < (unsigned)W) r.lm = row[gc0 - 1];
        if ((unsigned)(gc0 + 8) < (unsigned)W) r.rp = row[gc0 + 8];
    }
    return r;
}

// Build the shared pair-vectors for one row: E = even-aligned pairs,
// O = straddling pairs. Shared across the 4 gates -> v_pk_fma_f32.
__device__ __forceinline__ void row_vecs(const HRow& R, v2f E[4], v2f O[5]) {
    E[0] = (v2f){R.A.x, R.A.y};  E[1] = (v2f){R.A.z, R.A.w};
    E[2] = (v2f){R.B.x, R.B.y};  E[3] = (v2f){R.B.z, R.B.w};
    O[0] = (v2f){R.lm,  R.A.x};  O[1] = (v2f){R.A.y, R.A.z};
    O[2] = (v2f){R.A.w, R.B.x};  O[3] = (v2f){R.B.y, R.B.z};
    O[4] = (v2f){R.B.w, R.rp};
}

// Accumulate one conv row (3 taps, 4 gates) into acc.
__device__ __forceinline__ void acc_row_acc(const HRow& R, const float* __restrict__ wg,
                                            int wofs, v2f acc[4][4]) {
    v2f E[4], O[5];
    row_vecs(R, E, O);
#pragma unroll
    for (int co = 0; co < 4; ++co) {
        const float w0 = wg[co * 18 + wofs + 0];
        const float w1 = wg[co * 18 + wofs + 1];
        const float w2 = wg[co * 18 + wofs + 2];
        const v2f W0 = {w0, w0}, W1 = {w1, w1}, W2 = {w2, w2};
#pragma unroll
        for (int j = 0; j < 4; ++j) {
            acc[co][j] += W0 * O[j];
            acc[co][j] += W1 * E[j];
            acc[co][j] += W2 * O[j + 1];
        }
    }
}

// First conv row of a step: the first tap WRITES acc with `init` as the fma
// addend (BCAST: init[co] bias; else init[co*4+j], e.g. the hoisted x-conv).
// Removes the 32-mov accumulator init from every step.
template<bool BCAST>
__device__ __forceinline__ void acc_row_init(const HRow& R, const float* __restrict__ wg,
                                             int wofs, v2f acc[4][4],
                                             const v2f* __restrict__ init) {
    v2f E[4], O[5];
    row_vecs(R, E, O);
#pragma unroll
    for (int co = 0; co < 4; ++co) {
        const float w0 = wg[co * 18 + wofs + 0];
        const float w1 = wg[co * 18 + wofs + 1];
        const float w2 = wg[co * 18 + wofs + 2];
        const v2f W0 = {w0, w0}, W1 = {w1, w1}, W2 = {w2, w2};
#pragma unroll
        for (int j = 0; j < 4; ++j) {
            const v2f b = BCAST ? init[co] : init[co * 4 + j];
            acc[co][j] = W0 * O[j] + b;
            acc[co][j] += W1 * E[j];
            acc[co][j] += W2 * O[j + 1];
        }
    }
}

// NSTEPS fused conv-LSTM steps. Grid 512 (32 row-tiles x 16 col-tiles, 32x64
// interior each), 512 threads = 2 blocks/CU = 4 waves/EU. waves_per_eu(4,4)
// is LOAD-BEARING: launch_bounds(,4) only sets a MINIMUM, so the RA still
// chases 8 waves/EU (64-VGPR cap) and spills the prefetch to scratch (R2:
// VGPR=64 + 400MB scratch writes). Pinning (4,4) gives the true 128-reg
// budget; the prefetch then lives in registers.
// Per step: ds_reads issued first; x-conv consumes REGISTER-prefetched rows
// (covers LDS latency); next frame's rows prefetched under h-conv+gates;
// bias/xacc folded into the first tap's fma addend. setprio(1) across the
// compute body: 2 independent blocks/CU at drifting phases (attn-like
// regime, m191) lets compute-phase waves win issue over LDS-phase waves.
template<int NSTEPS, bool XC>
__global__ __launch_bounds__(NB)
__attribute__((amdgpu_waves_per_eu(4, 4)))
void fusedN(const float* __restrict__ xbase, size_t xstep,
            const float* __restrict__ hin, const float* __restrict__ cin,
            float* __restrict__ hout, float* __restrict__ cout_,
            const float* __restrict__ wg, const float* __restrict__ bg,
            float* __restrict__ dout, int zero_init)
{
    __shared__ float hT[2][LRN * LCW];
    const int tid = threadIdx.x;
    const int c0 = (blockIdx.x & 15) * TCOLS;
    const int r0 = (blockIdx.x >> 4) * TROWS;

    const bool has = tid < NSLOT;
    const int q   = tid / 10;             // slot row index 0..45
    const int jj  = tid - q * 10;         // col group 0..9
    const int lr  = 1 + q;                // local row 1..46
    const int lc  = 8 + 8 * jj;           // local col 8..80
    const int gr  = r0 - 8 + lr;          // global row of slot
    const int gc0 = c0 - 8 + 8 * jj;      // global col of slot (multiple of 8)
    const size_t gofs = (size_t)(gr + PADY) * XS + (gc0 + PADX);
    const bool inimg = ((unsigned)gr < (unsigned)H) && ((unsigned)gc0 < (unsigned)W);
    // raw-x fast path: all taps in rows [r0-9, r0+40], cols [c0-9, c0+80]
    const bool safe = (r0 >= 8) && (r0 + 40 <= H) && (c0 >= 16) && (c0 + 80 <= W);

    // ---- initial LDS h tile into buf0 (buf1 zeroed for hygiene) ----
    for (int idx = tid; idx < LRN * (LCV / 4); idx += NB) {
        const int r = idx / (LCV / 4);
        const int k = idx - r * (LCV / 4);
        float4 v = make_float4(0.f, 0.f, 0.f, 0.f);
        if (!zero_init)
            v = *(const float4*)(hin + (size_t)(r0 + r) * XS + (c0 + 4 * k));
        *(float4*)(&hT[0][r * LCW + 4 * k]) = v;
        *(float4*)(&hT[1][r * LCW + 4 * k]) = make_float4(0.f, 0.f, 0.f, 0.f);
    }

    // ---- c state in registers ----
    float cc[8];
    if (has && !zero_init) {
        const float4 a = *(const float4*)(cin + gofs);
        const float4 b = *(const float4*)(cin + gofs + 4);
        cc[0] = a.x; cc[1] = a.y; cc[2] = a.z; cc[3] = a.w;
        cc[4] = b.x; cc[5] = b.y; cc[6] = b.z; cc[7] = b.w;
    } else {
#pragma unroll
        for (int e = 0; e < 8; ++e) cc[e] = 0.f;
    }

    // ---- bias pairs (fma addend for the encoder's first tap) ----
    v2f bb4[4];
#pragma unroll
    for (int co = 0; co < 4; ++co) bb4[co] = (v2f){bg[co], bg[co]};

    // ---- decoder: hoist constant x-channel conv + bias into registers ----
    v2f xacc[4][4];
    if constexpr (XC) {
        if (has) {
#pragma unroll
            for (int co = 0; co < 4; ++co)
#pragma unroll
                for (int j = 0; j < 4; ++j) xacc[co][j] = bb4[co];
#pragma unroll
            for (int dy = 0; dy < 3; ++dy) {
                const HRow r = ld_row(xbase + gofs + (size_t)(dy - 1) * XS);
                acc_row_acc(r, wg, 3 * dy, xacc);
            }
        }
    }

    // ---- encoder: register-prefetch frame 0's three x rows ----
    HRow px0, px1, px2;
    if constexpr (!XC) {
        if (has) {
            if (safe) {
                const float* xp = xbase + (size_t)(gr - 1) * W + gc0;
                px0 = ld_row(xp);
                px1 = ld_row(xp + W);
                px2 = ld_row(xp + 2 * W);
            } else {
                px0 = ld_xrow_edge(xbase, gr - 1, gc0);
                px1 = ld_xrow_edge(xbase, gr,     gc0);
                px2 = ld_xrow_edge(xbase, gr + 1, gc0);
            }
        }
    }
    __syncthreads();

    float hh[8];
#pragma unroll
    for (int e = 0; e < 8; ++e) hh[e] = 0.f;

#pragma unroll
    for (int i = 1; i <= NSTEPS; ++i) {
        const float* hR = hT[(i + 1) & 1];   // holds h_{i-1}
        float* hW       = hT[i & 1];         // receives h_i
        const bool act = has && (lr >= i) && (lr < LRN - i);
        if (act) {
            __builtin_amdgcn_s_setprio(1);
            // issue the 12 LDS reads first; latency hides under the x-conv
            const float* hp = hR + (lr - 1) * LCW + lc;
            const HRow h0 = ld_row(hp);
            const HRow h1 = ld_row(hp + LCW);
            const HRow h2 = ld_row(hp + 2 * LCW);

            v2f acc[4][4];
            if constexpr (XC) {
                acc_row_init<false>(h0, wg, 9, acc, &xacc[0][0]);
                acc_row_acc(h1, wg, 9 + 3, acc);
                acc_row_acc(h2, wg, 9 + 6, acc);
            } else {
                // x-conv from the prefetched rows (bias folded into tap 0)
                acc_row_init<true>(px0, wg, 0, acc, bb4);
                acc_row_acc(px1, wg, 3, acc);
                acc_row_acc(px2, wg, 6, acc);
                // prefetch next frame's rows; vm latency spans h-conv + act
                if (i < NSTEPS) {
                    const float* xn = xbase + (size_t)i * xstep;
                    if (safe) {
                        const float* xp = xn + (size_t)(gr - 1) * W + gc0;
                        px0 = ld_row(xp);
                        px1 = ld_row(xp + W);
                        px2 = ld_row(xp + 2 * W);
                    } else {
                        px0 = ld_xrow_edge(xn, gr - 1, gc0);
                        px1 = ld_xrow_edge(xn, gr,     gc0);
                        px2 = ld_xrow_edge(xn, gr + 1, gc0);
                    }
                }
                acc_row_acc(h0, wg, 9, acc);
                acc_row_acc(h1, wg, 9 + 3, acc);
                acc_row_acc(h2, wg, 9 + 6, acc);
            }
#pragma unroll
            for (int jp = 0; jp < 4; ++jp) {
#pragma unroll
                for (int s = 0; s < 2; ++s) {
                    const int e = 2 * jp + s;
                    const float gi = sigm2_(acc[0][jp][s]);
                    const float gf = sigm2_(acc[1][jp][s]);
                    const float go = sigm2_(acc[2][jp][s]);
                    const float gg = tanhg2_(acc[3][jp][s]);
                    const float cn = gf * cc[e] + gi * gg;
                    cc[e] = cn;
                    hh[e] = inimg ? (go * tanhc_(cn)) : 0.f;  // SAME zero-pad
                }
            }
            *(float4*)(hW + lr * LCW + lc)     = make_float4(hh[0], hh[1], hh[2], hh[3]);
            *(float4*)(hW + lr * LCW + lc + 4) = make_float4(hh[4], hh[5], hh[6], hh[7]);
            __builtin_amdgcn_s_setprio(0);
        }
        __syncthreads();   // h_i visible; next step writes the other buffer
    }

    // ---- interior write-out: rows lr in [8,40), col groups jj in [1,8] ----
    if (has && lr >= 8 && lr < 8 + TROWS && jj >= 1 && jj <= 8) {
        if (dout) {
            const size_t o = (size_t)gr * W + gc0;
            *(float4*)(dout + o)     = make_float4(hh[0], hh[1], hh[2], hh[3]);
            *(float4*)(dout + o + 4) = make_float4(hh[4], hh[5], hh[6], hh[7]);
        } else {
            *(float4*)(hout + gofs)      = make_float4(hh[0], hh[1], hh[2], hh[3]);
            *(float4*)(hout + gofs + 4)  = make_float4(hh[4], hh[5], hh[6], hh[7]);
            *(float4*)(cout_ + gofs)     = make_float4(cc[0], cc[1], cc[2], cc[3]);
            *(float4*)(cout_ + gofs + 4) = make_float4(cc[4], cc[5], cc[6], cc[7]);
        }
    }
}

extern "C" void kernel_launch(void* const* d_in, const int* in_sizes, int n_in,
                              void* d_out, int out_size, void* d_ws, size_t ws_size,
                              hipStream_t stream) {
    const float* data  = (const float*)d_in[0];  // [20,1,1,1024,1024]
    const float* enc_w = (const float*)d_in[1];  // [4,2,3,3]
    const float* enc_b = (const float*)d_in[2];  // [4]
    const float* dec_w = (const float*)d_in[3];
    const float* dec_b = (const float*)d_in[4];
    // d_in[5..7] = epoch(0), T_en(20), T_de(20): constant device scalars;
    // loop counts hardcoded (host can't read device memory under capture).

    float* ws  = (float*)d_ws;
    float* hE1 = ws + 0 * FR;
    float* cE1 = ws + 1 * FR;
    float* hE0 = ws + 2 * FR;
    float* cE0 = ws + 3 * FR;
    float* hX  = ws + 4 * FR;
    float* cX  = ws + 5 * FR;
    float* wsc = ws + 6 * FR;             // scaled weights/biases (156 floats)
    const float* encW = wsc;
    const float* encB = wsc + 72;
    const float* decW = wsc + 80;
    const float* decB = wsc + 152;
    float* dout = (float*)d_out;
    // ws use: 6*FR*4 + 1KB ~= 26.4 MB (x is read raw; no padded frame copies)

    init_ws<<<2048, 256, 0, stream>>>(enc_w, enc_b, dec_w, dec_b, ws);

    dim3 blk(NB), grd(512);
    // encoder: steps 0-7, 8-15, 16-19 (x read raw from data)
    fusedN<8, false><<<grd, blk, 0, stream>>>(data,                     (size_t)NPIX,
                                              nullptr, nullptr, hE1, cE1, encW, encB, nullptr, 1);
    fusedN<8, false><<<grd, blk, 0, stream>>>(data + (size_t)8 * NPIX,  (size_t)NPIX,
                                              hE1, cE1, hE0, cE0, encW, encB, nullptr, 0);
    fusedN<4, false><<<grd, blk, 0, stream>>>(data + (size_t)16 * NPIX, (size_t)NPIX,
                                              hE0, cE0, hE1, cE1, encW, encB, nullptr, 0);
    // final encoder h in hE1 (constant decoder input; zero halo ring = SAME pad)
    fusedN<8, true><<<grd, blk, 0, stream>>>(hE1, 0, nullptr, nullptr,
                                             hE0, cE0, decW, decB, nullptr, 1);
    fusedN<8, true><<<grd, blk, 0, stream>>>(hE1, 0, hE0, cE0,
                                             hX,  cX,  decW, decB, nullptr, 0);
    fusedN<4, true><<<grd, blk, 0, stream>>>(hE1, 0, hX,  cX,
                                             nullptr, nullptr, decW, decB, dout, 0);
}

// Round 5
// 349.865 us; speedup vs baseline: 3.1805x; 1.8432x over previous
//
#include <hip/hip_runtime.h>

#define W 1024
#define H 1024
#define PADX 16                       // col zero-pad each side (state/h buffers)
#define PADY 8                        // row zero-pad each side
#define XS 1056                       // padded row stride (floats)
#define YS 1040                       // padded row count
#define FR ((size_t)XS * (size_t)YS)  // floats per padded buffer
#define NPIX (H * W)
#define TROWS 32                      // tile rows per block
#define TCOLS 64                      // tile cols per block
#define LRN 48                        // local rows: gr in [r0-8, r0+40)
#define LCV 96                        // valid local cols: gc in [c0-16, c0+80)
#define LCW 100                       // LDS row stride (pad 4 to stagger banks)
#define NSLOT 460                     // 46 rows x 10 col-groups (8 px each)
#define NB 512
#define LOG2E 1.4426950408889634f
#define TWOL  2.8853900817779268f     // 2*log2(e)

typedef float v2f __attribute__((ext_vector_type(2)));

__device__ __forceinline__ float frcp_(float v) { return __builtin_amdgcn_rcpf(v); }
__device__ __forceinline__ float exp2_(float v) { return __builtin_amdgcn_exp2f(v); }

// Zero the 6 padded state buffers (ws[0..6FR)) and write log2e-scaled weight
// copies at ws+6FR:  enc_w[0..72) enc_b[72..76) dec_w[80..152) dec_b[152..156).
// Gate pre-activations i,f,o scaled by log2(e), g by 2*log2(e): exp2 needs no
// per-element multiply.
__global__ __launch_bounds__(256) void init_ws(const float* __restrict__ ew,
                                               const float* __restrict__ eb,
                                               const float* __restrict__ dw,
                                               const float* __restrict__ db,
                                               float* __restrict__ ws) {
    const size_t n4 = 6 * (FR / 4);
    size_t i = (size_t)blockIdx.x * blockDim.x + threadIdx.x;
    const size_t stride = (size_t)gridDim.x * blockDim.x;
    float4* w4 = (float4*)ws;
    const float4 z = make_float4(0.f, 0.f, 0.f, 0.f);
    for (; i < n4; i += stride) w4[i] = z;
    if (blockIdx.x == 0) {
        float* wsc = ws + 6 * FR;
        const int t = threadIdx.x;
        if (t < 72)                   wsc[t] = ew[t] * ((t / 18 == 3) ? TWOL : LOG2E);
        else if (t < 76)              wsc[t] = eb[t - 72] * ((t - 72 == 3) ? TWOL : LOG2E);
        else if (t >= 80 && t < 152)  wsc[t] = dw[t - 80] * (((t - 80) / 18 == 3) ? TWOL : LOG2E);
        else if (t >= 152 && t < 156) wsc[t] = db[t - 152] * ((t - 152 == 3) ? TWOL : LOG2E);
    }
}

// Accumulate one 3-tap conv row over an 8-px slot into acc[4][4] (output pairs).
// Pair vectors built once per row, shared across the 4 gates -> v_pk_fma_f32.
__device__ __forceinline__ void acc_row(float4 A, float4 Bq, float lm, float rp,
                                        const float* __restrict__ wg, int wofs, int dy,
                                        v2f acc[4][4]) {
    const v2f E0 = {A.x, A.y},  E1 = {A.z, A.w};
    const v2f E2 = {Bq.x, Bq.y}, E3 = {Bq.z, Bq.w};
    const v2f O0 = {lm, A.x},   O1 = {A.y, A.z};
    const v2f O2 = {A.w, Bq.x}, O3 = {Bq.y, Bq.z}, O4 = {Bq.w, rp};
#pragma unroll
    for (int co = 0; co < 4; ++co) {
        const float w0 = wg[co * 18 + wofs + dy * 3 + 0];
        const float w1 = wg[co * 18 + wofs + dy * 3 + 1];
        const float w2 = wg[co * 18 + wofs + dy * 3 + 2];
        const v2f W0 = {w0, w0}, W1 = {w1, w1}, W2 = {w2, w2};
        acc[co][0] += W0 * O0 + W1 * E0 + W2 * O1;
        acc[co][1] += W0 * O1 + W1 * E1 + W2 * O2;
        acc[co][2] += W0 * O2 + W1 * E2 + W2 * O3;
        acc[co][3] += W0 * O3 + W1 * E3 + W2 * O4;
    }
}

// Unchecked 3-row conv of one channel; p = slot top-left (row gr-1, col gc0).
__device__ __forceinline__ void conv3x8_pk(const float* __restrict__ p, int stride,
                                           const float* __restrict__ wg, int wofs,
                                           v2f acc[4][4]) {
#pragma unroll
    for (int dy = 0; dy < 3; ++dy) {
        acc_row(*(const float4*)p, *(const float4*)(p + 4), p[-1], p[8], wg, wofs, dy, acc);
        p += stride;
    }
}

// Boundary-checked conv over the RAW (unpadded) x frame: SAME zero padding via
// masked loads. gc0 is a multiple of 8, so the float4 pair is all-in or all-out.
__device__ __forceinline__ void conv3x8_edge(const float* __restrict__ base, int gr, int gc0,
                                             const float* __restrict__ wg, int wofs,
                                             v2f acc[4][4]) {
    const bool colA = (unsigned)gc0 < (unsigned)W;
    const bool lmok = (unsigned)(gc0 - 1) < (unsigned)W;
    const bool rpok = (unsigned)(gc0 + 8) < (unsigned)W;
#pragma unroll
    for (int dy = 0; dy < 3; ++dy) {
        const int ry = gr - 1 + dy;
        const bool rok = (unsigned)ry < (unsigned)H;
        const float* row = base + (long)ry * W;
        float4 A = make_float4(0.f, 0.f, 0.f, 0.f);
        float4 Bq = make_float4(0.f, 0.f, 0.f, 0.f);
        float lm = 0.f, rp = 0.f;
        if (rok) {
            if (colA) { A = *(const float4*)(row + gc0); Bq = *(const float4*)(row + gc0 + 4); }
            if (lmok) lm = row[gc0 - 1];
            if (rpok) rp = row[gc0 + 8];
        }
        acc_row(A, Bq, lm, rp, wg, wofs, dy, acc);
    }
}

// NSTEPS fused conv-LSTM steps. Grid 512 (32 row-tiles x 16 col-tiles, 32x64
// interior each), 512 threads = 2 blocks/CU = 4 waves/EU. h tile double-
// buffered in LDS (one barrier/step); c in registers.
// This round's step body:
//  - middle conv row (dy=1) comes from REGISTERS: the thread's own row lr of
//    h_{i-1} is exactly its hh from last step; only lm/rp (2 scalars) come
//    from LDS. 12 -> 10 LDS reads/step and the dy=1 conv (48 pk-fma) starts
//    right after the barrier with ~no LDS wait. hh dies before the x-conv so
//    peak register pressure stays at the R1 no-spill equilibrium.
//  - gate math rcp-fused: 10 -> 7 trans/px (5 exp2 + 2 rcp), the trans pipe
//    being the dominant busy-cycle consumer (R4 post-mortem arithmetic).
template<int NSTEPS, bool XC>
__global__ __launch_bounds__(NB)
__attribute__((amdgpu_waves_per_eu(4, 4)))
void fusedN(const float* __restrict__ xbase, size_t xstep,
            const float* __restrict__ hin, const float* __restrict__ cin,
            float* __restrict__ hout, float* __restrict__ cout_,
            const float* __restrict__ wg, const float* __restrict__ bg,
            float* __restrict__ dout, int zero_init)
{
    __shared__ float hT[2][LRN * LCW];
    const int tid = threadIdx.x;
    const int c0 = (blockIdx.x & 15) * TCOLS;
    const int r0 = (blockIdx.x >> 4) * TROWS;

    const bool has = tid < NSLOT;
    const int q   = tid / 10;             // slot row index 0..45
    const int jj  = tid - q * 10;         // col group 0..9
    const int lr  = 1 + q;                // local row 1..46
    const int lc  = 8 + 8 * jj;           // local col 8..80
    const int gr  = r0 - 8 + lr;          // global row of slot
    const int gc0 = c0 - 8 + 8 * jj;      // global col of slot (multiple of 8)
    const size_t gofs = (size_t)(gr + PADY) * XS + (gc0 + PADX);
    const bool inimg = ((unsigned)gr < (unsigned)H) && ((unsigned)gc0 < (unsigned)W);
    // raw-x fast path: all taps in rows [r0-9, r0+40], cols [c0-9, c0+80]
    const bool safe = (r0 >= 8) && (r0 + 40 <= H) && (c0 >= 16) && (c0 + 80 <= W);

    // ---- initial LDS h tile into buf0 (buf1 zeroed for hygiene) ----
    for (int idx = tid; idx < LRN * (LCV / 4); idx += NB) {
        const int r = idx / (LCV / 4);
        const int k = idx - r * (LCV / 4);
        float4 v = make_float4(0.f, 0.f, 0.f, 0.f);
        if (!zero_init)
            v = *(const float4*)(hin + (size_t)(r0 + r) * XS + (c0 + 4 * k));
        *(float4*)(&hT[0][r * LCW + 4 * k]) = v;
        *(float4*)(&hT[1][r * LCW + 4 * k]) = make_float4(0.f, 0.f, 0.f, 0.f);
    }

    // ---- c state in registers; hh seeded with h_{t0}[row lr] (== LDS row lr,
    //      the register copy of the middle conv row for step 1) ----
    float cc[8], hh[8];
    if (has && !zero_init) {
        const float4 a = *(const float4*)(cin + gofs);
        const float4 b = *(const float4*)(cin + gofs + 4);
        cc[0] = a.x; cc[1] = a.y; cc[2] = a.z; cc[3] = a.w;
        cc[4] = b.x; cc[5] = b.y; cc[6] = b.z; cc[7] = b.w;
        const float4 ha = *(const float4*)(hin + gofs);
        const float4 hb = *(const float4*)(hin + gofs + 4);
        hh[0] = ha.x; hh[1] = ha.y; hh[2] = ha.z; hh[3] = ha.w;
        hh[4] = hb.x; hh[5] = hb.y; hh[6] = hb.z; hh[7] = hb.w;
    } else {
#pragma unroll
        for (int e = 0; e < 8; ++e) { cc[e] = 0.f; hh[e] = 0.f; }
    }

    // ---- decoder: hoist constant x-channel conv + bias into registers ----
    v2f xacc[4][4];
    if constexpr (XC) {
        if (has) {
#pragma unroll
            for (int co = 0; co < 4; ++co) {
                const v2f bb = {bg[co], bg[co]};
#pragma unroll
                for (int j = 0; j < 4; ++j) xacc[co][j] = bb;
            }
            conv3x8_pk(xbase + gofs - XS, XS, wg, 0, xacc);
        }
    }
    __syncthreads();

#pragma unroll
    for (int i = 1; i <= NSTEPS; ++i) {
        const float* hR = hT[(i + 1) & 1];   // holds h_{i-1}
        float* hW       = hT[i & 1];         // receives h_i
        const bool act = has && (lr >= i) && (lr < LRN - i);
        if (act) {
            __builtin_amdgcn_s_setprio(1);
            const float* hp = hR + (lr - 1) * LCW + lc;
            // middle-row halo scalars (own row lr, cols lc-1 / lc+8)
            const float mlm = hp[LCW - 1];
            const float mrp = hp[LCW + 8];

            v2f acc[4][4];
            if constexpr (XC) {
#pragma unroll
                for (int co = 0; co < 4; ++co)
#pragma unroll
                    for (int j = 0; j < 4; ++j) acc[co][j] = xacc[co][j];
            } else {
#pragma unroll
                for (int co = 0; co < 4; ++co) {
                    const v2f bb = {bg[co], bg[co]};
#pragma unroll
                    for (int j = 0; j < 4; ++j) acc[co][j] = bb;
                }
            }
            // middle conv row (dy=1) from registers: starts immediately
            acc_row(make_float4(hh[0], hh[1], hh[2], hh[3]),
                    make_float4(hh[4], hh[5], hh[6], hh[7]),
                    mlm, mrp, wg, 9, 1, acc);
            // encoder: x-channel conv (global); its latency rides under this
            if constexpr (!XC) {
                const float* xp = xbase + (size_t)(i - 1) * xstep;
                if (safe)
                    conv3x8_pk(xp + (size_t)(gr - 1) * W + gc0, W, wg, 0, acc);
                else
                    conv3x8_edge(xp, gr, gc0, wg, 0, acc);
            }
            // outer conv rows (lr-1, lr+1) from LDS
            acc_row(*(const float4*)hp, *(const float4*)(hp + 4),
                    hp[-1], hp[8], wg, 9, 0, acc);
            const float* hq = hp + 2 * LCW;
            acc_row(*(const float4*)hq, *(const float4*)(hq + 4),
                    hq[-1], hq[8], wg, 9, 2, acc);

            // ---- rcp-fused gates: 5 exp2 + 2 rcp per px (was 5+5) ----
            // cn = [c(1+Eg)(1+Ei) + (Eg-1)(1+Ef)] / [(1+Ef)(1+Eg)(1+Ei)]
            // h  = (Ec-1) / ((1+Eo)(1+Ec)),  Ec = 2^(2log2e * cn)
#pragma unroll
            for (int jp = 0; jp < 4; ++jp) {
#pragma unroll
                for (int s = 0; s < 2; ++s) {
                    const int e = 2 * jp + s;
                    const float Ei = exp2_(-acc[0][jp][s]);
                    const float Ef = exp2_(-acc[1][jp][s]);
                    const float Eo = exp2_(-acc[2][jp][s]);
                    const float Eg = exp2_(acc[3][jp][s]);
                    const float P  = (1.f + Eg) * (1.f + Ei);
                    const float Q  = 1.f + Ef;
                    const float cn = (cc[e] * P + (Eg - 1.f) * Q) * frcp_(P * Q);
                    cc[e] = cn;
                    const float Ec = exp2_(TWOL * cn);
                    const float hv = (Ec - 1.f) * frcp_((1.f + Eo) * (1.f + Ec));
                    hh[e] = inimg ? hv : 0.f;   // SAME zero-pad
                }
            }
            *(float4*)(hW + lr * LCW + lc)     = make_float4(hh[0], hh[1], hh[2], hh[3]);
            *(float4*)(hW + lr * LCW + lc + 4) = make_float4(hh[4], hh[5], hh[6], hh[7]);
            __builtin_amdgcn_s_setprio(0);
        }
        __syncthreads();   // h_i visible; next step writes the other buffer
    }

    // ---- interior write-out: rows lr in [8,40), col groups jj in [1,8] ----
    if (has && lr >= 8 && lr < 8 + TROWS && jj >= 1 && jj <= 8) {
        if (dout) {
            const size_t o = (size_t)gr * W + gc0;
            *(float4*)(dout + o)     = make_float4(hh[0], hh[1], hh[2], hh[3]);
            *(float4*)(dout + o + 4) = make_float4(hh[4], hh[5], hh[6], hh[7]);
        } else {
            *(float4*)(hout + gofs)      = make_float4(hh[0], hh[1], hh[2], hh[3]);
            *(float4*)(hout + gofs + 4)  = make_float4(hh[4], hh[5], hh[6], hh[7]);
            *(float4*)(cout_ + gofs)     = make_float4(cc[0], cc[1], cc[2], cc[3]);
            *(float4*)(cout_ + gofs + 4) = make_float4(cc[4], cc[5], cc[6], cc[7]);
        }
    }
}

extern "C" void kernel_launch(void* const* d_in, const int* in_sizes, int n_in,
                              void* d_out, int out_size, void* d_ws, size_t ws_size,
                              hipStream_t stream) {
    const float* data  = (const float*)d_in[0];  // [20,1,1,1024,1024]
    const float* enc_w = (const float*)d_in[1];  // [4,2,3,3]
    const float* enc_b = (const float*)d_in[2];  // [4]
    const float* dec_w = (const float*)d_in[3];
    const float* dec_b = (const float*)d_in[4];
    // d_in[5..7] = epoch(0), T_en(20), T_de(20): constant device scalars;
    // loop counts hardcoded (host can't read device memory under capture).

    float* ws  = (float*)d_ws;
    float* hE1 = ws + 0 * FR;
    float* cE1 = ws + 1 * FR;
    float* hE0 = ws + 2 * FR;
    float* cE0 = ws + 3 * FR;
    float* hX  = ws + 4 * FR;
    float* cX  = ws + 5 * FR;
    float* wsc = ws + 6 * FR;             // scaled weights/biases (156 floats)
    const float* encW = wsc;
    const float* encB = wsc + 72;
    const float* decW = wsc + 80;
    const float* decB = wsc + 152;
    float* dout = (float*)d_out;
    // ws use: 6*FR*4 + 1KB ~= 26.4 MB (x is read raw; no padded frame copies)

    init_ws<<<2048, 256, 0, stream>>>(enc_w, enc_b, dec_w, dec_b, ws);

    dim3 blk(NB), grd(512);
    // encoder: steps 0-7, 8-15, 16-19 (x read raw from data)
    fusedN<8, false><<<grd, blk, 0, stream>>>(data,                     (size_t)NPIX,
                                              nullptr, nullptr, hE1, cE1, encW, encB, nullptr, 1);
    fusedN<8, false><<<grd, blk, 0, stream>>>(data + (size_t)8 * NPIX,  (size_t)NPIX,
                                              hE1, cE1, hE0, cE0, encW, encB, nullptr, 0);
    fusedN<4, false><<<grd, blk, 0, stream>>>(data + (size_t)16 * NPIX, (size_t)NPIX,
                                              hE0, cE0, hE1, cE1, encW, encB, nullptr, 0);
    // final encoder h in hE1 (constant decoder input; zero halo ring = SAME pad)
    fusedN<8, true><<<grd, blk, 0, stream>>>(hE1, 0, nullptr, nullptr,
                                             hE0, cE0, decW, decB, nullptr, 1);
    fusedN<8, true><<<grd, blk, 0, stream>>>(hE1, 0, hE0, cE0,
                                             hX,  cX,  decW, decB, nullptr, 0);
    fusedN<4, true><<<grd, blk, 0, stream>>>(hE1, 0, hX,  cX,
                                             nullptr, nullptr, decW, decB, dout, 0);
}